// Round 5
// baseline (157.189 us; speedup 1.0000x reference)
//
#include <hip/hip_runtime.h>

#define NN 100
#define CC 32
#define HEE 32
#define FF 64
#define TILE 10
#define ROWS 7  // rows per wave in k_layer

// ---------------- K1: hi = x@ew1[:C]+eb1, hj = x@ew1[C:], d0 ----------------
__global__ __launch_bounds__(64) void k_hidden(
    const float* __restrict__ x, const float* __restrict__ A,
    const float* __restrict__ ew1, const float* __restrict__ eb1,
    float* __restrict__ hi, float* __restrict__ hj, float* __restrict__ d0) {
  int bn = blockIdx.x;
  int t = threadIdx.x;
  __shared__ float xr[CC];
  if (t < CC) xr[t] = x[bn * CC + t];

  const float* arow = A + (size_t)bn * NN;
  float s = 0.f;
  for (int j = t; j < NN; j += 64) s += arow[j];
#pragma unroll
  for (int off = 32; off > 0; off >>= 1) s += __shfl_down(s, off);
  if (t == 0) d0[bn] = 1.0f / sqrtf(s + 1.0f + 1e-5f);

  __syncthreads();
  int k = t & 31;
  const float* w = ew1 + (t < 32 ? 0 : CC * HEE) + k;
  float acc = (t < 32) ? eb1[k] : 0.f;
#pragma unroll
  for (int c = 0; c < CC; ++c) acc += xr[c] * w[c * HEE];
  if (t < 32) hi[bn * HEE + k] = acc;
  else        hj[bn * HEE + k] = acc;
}

// ---------------- K2: Ahat1 = A_pred + I, d1 ----------------
__global__ __launch_bounds__(256) void k_edge(
    const float* __restrict__ hi, const float* __restrict__ hj,
    const float* __restrict__ ew2, const float* __restrict__ eb2,
    const float* __restrict__ mask,
    float* __restrict__ Ahat1, float* __restrict__ d1) {
  __shared__ __align__(16) float shi[NN * HEE];
  __shared__ __align__(16) float shj[NN * HEE];
  __shared__ __align__(16) float sw2[HEE];
  __shared__ float sm[NN];
  __shared__ float sA[TILE][NN];
  int t = threadIdx.x;
  int b = blockIdx.x / 10;
  int i0 = (blockIdx.x % 10) * TILE;

  const float4* hi4 = (const float4*)(hi + (size_t)b * NN * HEE);
  const float4* hj4 = (const float4*)(hj + (size_t)b * NN * HEE);
  float4* shi4 = (float4*)shi;
  float4* shj4 = (float4*)shj;
  for (int v = t; v < NN * 8; v += 256) {
    int j = v >> 3, k4 = v & 7;
    int sw = (j << 3) | (k4 ^ (j & 7));
    shi4[sw] = hi4[v];
    shj4[sw] = hj4[v];
  }
  if (t < HEE) sw2[t] = ew2[t];
  if (t < NN) sm[t] = mask[b * NN + t];
  __syncthreads();

  float e2 = eb2[0];
  float4* sw24 = (float4*)sw2;
  for (int p = t; p < TILE * NN; p += 256) {
    int r = p / NN, j = p % NN, i = i0 + r;
    float val;
    if (j == i) {
      val = 1.0f;
    } else {
      float a1 = 0.f, a2 = 0.f;
#pragma unroll
      for (int k4 = 0; k4 < 8; ++k4) {
        float4 hii = shi4[(i << 3) | (k4 ^ (i & 7))];
        float4 hji = shj4[(i << 3) | (k4 ^ (i & 7))];
        float4 hij = shi4[(j << 3) | (k4 ^ (j & 7))];
        float4 hjj = shj4[(j << 3) | (k4 ^ (j & 7))];
        float4 w4 = sw24[k4];
        a1 += fmaxf(hii.x + hjj.x, 0.f) * w4.x;
        a2 += fmaxf(hij.x + hji.x, 0.f) * w4.x;
        a1 += fmaxf(hii.y + hjj.y, 0.f) * w4.y;
        a2 += fmaxf(hij.y + hji.y, 0.f) * w4.y;
        a1 += fmaxf(hii.z + hjj.z, 0.f) * w4.z;
        a2 += fmaxf(hij.z + hji.z, 0.f) * w4.z;
        a1 += fmaxf(hii.w + hjj.w, 0.f) * w4.w;
        a2 += fmaxf(hij.w + hji.w, 0.f) * w4.w;
      }
      val = expf(0.5f * (a1 + a2) + e2) * sm[i] * sm[j];
    }
    sA[r][j] = val;
    Ahat1[((size_t)b * NN + i) * NN + j] = val;
  }
  __syncthreads();
  if (t < TILE) {
    float s = 0.f;
    for (int j = 0; j < NN; ++j) s += sA[t][j];
    d1[b * NN + i0 + t] = 1.0f / sqrtf(s + 1e-5f);
  }
}

// ---------------- K_pre: P[b][rel][i][f] = sum_c x[b][i][c] * gw0[rel*32+c][f] ----------------
__global__ __launch_bounds__(256, 2) void k_pre2(
    const float* __restrict__ x, const float* __restrict__ gw0,
    float* __restrict__ P) {
  int t = threadIdx.x;
  int b = blockIdx.x & 127;
  int q = blockIdx.x >> 7;
  int wid = __builtin_amdgcn_readfirstlane(t >> 6);
  int lane = t & 63;
  int rg = wid * 4 + q;
  int row0 = rg * 8;
  if (row0 >= NN) return;

  int rowc[8];
#pragma unroll
  for (int r = 0; r < 8; ++r) rowc[r] = min(row0 + r, NN - 1);

  float acc0[8], acc1[8];
#pragma unroll
  for (int r = 0; r < 8; ++r) { acc0[r] = 0.f; acc1[r] = 0.f; }

  for (int c4 = 0; c4 < CC / 4; ++c4) {
    int c = c4 * 4;
    float w00 = gw0[(size_t)c * 64 + lane];
    float w01 = gw0[(size_t)(c + 1) * 64 + lane];
    float w02 = gw0[(size_t)(c + 2) * 64 + lane];
    float w03 = gw0[(size_t)(c + 3) * 64 + lane];
    float w10 = gw0[(size_t)(CC + c) * 64 + lane];
    float w11 = gw0[(size_t)(CC + c + 1) * 64 + lane];
    float w12 = gw0[(size_t)(CC + c + 2) * 64 + lane];
    float w13 = gw0[(size_t)(CC + c + 3) * 64 + lane];
#pragma unroll
    for (int r = 0; r < 8; ++r) {
      float4 a4 = *(const float4*)(x + ((size_t)b * NN + rowc[r]) * CC + c);
      acc0[r] += a4.x * w00 + a4.y * w01 + a4.z * w02 + a4.w * w03;
      acc1[r] += a4.x * w10 + a4.y * w11 + a4.z * w12 + a4.w * w13;
    }
  }
#pragma unroll
  for (int r = 0; r < 8; ++r) {
    int row = row0 + r;
    if (row < NN) {
      P[(((size_t)b * 2 + 0) * NN + row) * 64 + lane] = acc0[r];
      P[(((size_t)b * 2 + 1) * NN + row) * 64 + lane] = acc1[r];
    }
  }
}

// ---------------- K_layer ----------------
// grid B*4, 256 threads. Block owns 25-row strip; wave owns 7 rows (overlap rows
// compute identical values -> benign duplicate writes).
// Manual 1-chunk-ahead software pipeline hides A/Ah scalar-load latency.
template <int LAST>
__global__ __launch_bounds__(256, 2) void k_layer(
    const float* __restrict__ A, const float* __restrict__ Ah1,
    const float* __restrict__ d0, const float* __restrict__ d1,
    const float* __restrict__ mask, const float* __restrict__ Pin,
    const float* __restrict__ bias, const float* __restrict__ Wn,
    float* __restrict__ Pout) {
  __shared__ __align__(16) float sP[2][NN][64];     // P scaled by d[j]
  __shared__ __align__(16) float srow[4][ROWS][64]; // per-wave out rows
  int t = threadIdx.x;
  int b = blockIdx.x >> 2;
  int q = blockIdx.x & 3;

  // stage sP[rel][j][f] = P[b][rel][j][f] * d_rel[j]
  {
    const float4* P4 = (const float4*)(Pin + (size_t)b * 12800);
    float4* sP4 = (float4*)&sP[0][0][0];
    const float* d0b = d0 + b * NN;
    const float* d1b = d1 + b * NN;
    for (int v = t; v < 3200; v += 256) {
      int rel = (v >= 1600) ? 1 : 0;
      int rem = v - rel * 1600;
      int j = rem >> 4;
      float dv = rel ? d1b[j] : d0b[j];
      float4 p = P4[v];
      p.x *= dv; p.y *= dv; p.z *= dv; p.w *= dv;
      sP4[v] = p;
    }
  }
  __syncthreads();

  int wid = __builtin_amdgcn_readfirstlane(t >> 6);
  int lane = t & 63;
  int row0 = q * 25 + wid * ROWS;

  int rowc[ROWS];
#pragma unroll
  for (int r = 0; r < ROWS; ++r) rowc[r] = min(row0 + r, NN - 1);

  float acc0[ROWS], acc1[ROWS];
#pragma unroll
  for (int r = 0; r < ROWS; ++r) { acc0[r] = 0.f; acc1[r] = 0.f; }

  const float* A_b = A + (size_t)b * NN * NN;
  const float* Ah_b = Ah1 + (size_t)b * NN * NN;

  // ---- phase 1: software-pipelined over j4 chunks ----
  float4 ca0[ROWS], ca1[ROWS];
  float cp0[4], cp1[4];
#pragma unroll
  for (int r = 0; r < ROWS; ++r) {
    ca0[r] = *(const float4*)(A_b + (size_t)rowc[r] * NN);
    ca1[r] = *(const float4*)(Ah_b + (size_t)rowc[r] * NN);
  }
#pragma unroll
  for (int u = 0; u < 4; ++u) { cp0[u] = sP[0][u][lane]; cp1[u] = sP[1][u][lane]; }

#pragma unroll 1
  for (int j4 = 0; j4 < 25; ++j4) {
    int jn = (j4 < 24) ? (j4 + 1) * 4 : 0;  // wrap: last prefetch unused
    float4 na0[ROWS], na1[ROWS];
    float np0[4], np1[4];
#pragma unroll
    for (int r = 0; r < ROWS; ++r) {
      na0[r] = *(const float4*)(A_b + (size_t)rowc[r] * NN + jn);
      na1[r] = *(const float4*)(Ah_b + (size_t)rowc[r] * NN + jn);
    }
#pragma unroll
    for (int u = 0; u < 4; ++u) { np0[u] = sP[0][jn + u][lane]; np1[u] = sP[1][jn + u][lane]; }
#pragma unroll
    for (int r = 0; r < ROWS; ++r) {
      acc0[r] += ca0[r].x * cp0[0] + ca0[r].y * cp0[1] + ca0[r].z * cp0[2] + ca0[r].w * cp0[3];
      acc1[r] += ca1[r].x * cp1[0] + ca1[r].y * cp1[1] + ca1[r].z * cp1[2] + ca1[r].w * cp1[3];
    }
#pragma unroll
    for (int r = 0; r < ROWS; ++r) { ca0[r] = na0[r]; ca1[r] = na1[r]; }
#pragma unroll
    for (int u = 0; u < 4; ++u) { cp0[u] = np0[u]; cp1[u] = np1[u]; }
  }

  float vb = bias[lane];
  const float* d0b = d0 + b * NN;
  const float* d1b = d1 + b * NN;
  const float* mb = mask + b * NN;
  float outv[ROWS];
#pragma unroll
  for (int r = 0; r < ROWS; ++r) {
    float d0r = d0b[rowc[r]];
    float d1r = d1b[rowc[r]];
    float mr = mb[rowc[r]];
    float pdiag = sP[0][rowc[r]][lane];  // +I term of rel0
    float v = (acc0[r] + pdiag) * d0r + acc1[r] * d1r;
    v = (v + vb) * mr;
    outv[r] = fmaxf(v, 0.f);
  }

  if (LAST) {
    float mx = outv[0];
#pragma unroll
    for (int r = 1; r < ROWS; ++r) mx = fmaxf(mx, outv[r]);
    Pout[((size_t)b * 16 + q * 4 + wid) * 64 + lane] = mx;
    return;
  }

  // ---- phase 2: P_next = out @ Wn (srow wave-private, no barrier) ----
#pragma unroll
  for (int r = 0; r < ROWS; ++r) srow[wid][r][lane] = outv[r];

  float pacc0[ROWS], pacc1[ROWS];
#pragma unroll
  for (int r = 0; r < ROWS; ++r) { pacc0[r] = 0.f; pacc1[r] = 0.f; }

  float cw0[4], cw1[4];
#pragma unroll
  for (int u = 0; u < 4; ++u) {
    cw0[u] = Wn[(size_t)u * 64 + lane];
    cw1[u] = Wn[(size_t)(64 + u) * 64 + lane];
  }
#pragma unroll 1
  for (int k4 = 0; k4 < 16; ++k4) {
    int kn = (k4 < 15) ? (k4 + 1) * 4 : 0;
    float nw0[4], nw1[4];
#pragma unroll
    for (int u = 0; u < 4; ++u) {
      nw0[u] = Wn[(size_t)(kn + u) * 64 + lane];
      nw1[u] = Wn[(size_t)(64 + kn + u) * 64 + lane];
    }
    int k = k4 * 4;
#pragma unroll
    for (int r = 0; r < ROWS; ++r) {
      float4 s4 = *(const float4*)&srow[wid][r][k];  // broadcast read
      pacc0[r] += s4.x * cw0[0] + s4.y * cw0[1] + s4.z * cw0[2] + s4.w * cw0[3];
      pacc1[r] += s4.x * cw1[0] + s4.y * cw1[1] + s4.z * cw1[2] + s4.w * cw1[3];
    }
#pragma unroll
    for (int u = 0; u < 4; ++u) { cw0[u] = nw0[u]; cw1[u] = nw1[u]; }
  }
#pragma unroll
  for (int r = 0; r < ROWS; ++r) {
    int row = row0 + r;
    if (row < NN) {
      Pout[(((size_t)b * 2 + 0) * NN + row) * 64 + lane] = pacc0[r];
      Pout[(((size_t)b * 2 + 1) * NN + row) * 64 + lane] = pacc1[r];
    }
  }
}

// ---------------- K_final: max over 16 rowgroup partials + classifier ----------------
__global__ __launch_bounds__(64) void k_final(
    const float* __restrict__ pooled, const float* __restrict__ fw,
    const float* __restrict__ fb, float* __restrict__ out) {
  int b = blockIdx.x;
  int t = threadIdx.x;
  __shared__ float sp[FF];
  float m = -3.402823466e38f;
  const float* pb = pooled + (size_t)b * 16 * 64;
#pragma unroll
  for (int rg = 0; rg < 16; ++rg) m = fmaxf(m, pb[rg * 64 + t]);
  sp[t] = m;
  __syncthreads();
  if (t < 16) {
    float acc = fb[t];
#pragma unroll
    for (int f = 0; f < FF; ++f) acc += sp[f] * fw[f * 16 + t];
    out[b * 16 + t] = acc;
  }
}

extern "C" void kernel_launch(void* const* d_in, const int* in_sizes, int n_in,
                              void* d_out, int out_size, void* d_ws, size_t ws_size,
                              hipStream_t stream) {
  const float* x    = (const float*)d_in[0];
  const float* A    = (const float*)d_in[1];
  const float* mask = (const float*)d_in[2];
  const float* ew1  = (const float*)d_in[3];
  const float* eb1  = (const float*)d_in[4];
  const float* ew2  = (const float*)d_in[5];
  const float* eb2  = (const float*)d_in[6];
  const float* gw0  = (const float*)d_in[7];
  const float* gb0  = (const float*)d_in[8];
  const float* gw1  = (const float*)d_in[9];
  const float* gb1  = (const float*)d_in[10];
  const float* gw2  = (const float*)d_in[11];
  const float* gb2  = (const float*)d_in[12];
  const float* fw   = (const float*)d_in[13];
  const float* fb   = (const float*)d_in[14];
  float* out = (float*)d_out;
  float* ws = (float*)d_ws;

  const int B = 128;
  float* hi  = ws;                   // 409600
  float* hj  = hi + 409600;          // 409600
  float* Ah1 = hj + 409600;          // 1280000
  float* d0  = Ah1 + 1280000;        // 12800
  float* d1  = d0 + 12800;           // 12800
  float* Pa  = d1 + 12800;           // 1638400  [B][2][100][64]
  float* Pb  = Pa + 1638400;         // 1638400
  float* pooled = Pb + 1638400;      // 128*16*64 = 131072

  k_hidden<<<B * NN, 64, 0, stream>>>(x, A, ew1, eb1, hi, hj, d0);
  k_edge<<<B * 10, 256, 0, stream>>>(hi, hj, ew2, eb2, mask, Ah1, d1);
  k_pre2<<<512, 256, 0, stream>>>(x, gw0, Pa);
  k_layer<0><<<B * 4, 256, 0, stream>>>(A, Ah1, d0, d1, mask, Pa, gb0, gw1, Pb);
  k_layer<0><<<B * 4, 256, 0, stream>>>(A, Ah1, d0, d1, mask, Pb, gb1, gw2, Pa);
  k_layer<1><<<B * 4, 256, 0, stream>>>(A, Ah1, d0, d1, mask, Pa, gb2, gw2, pooled);
  k_final<<<B, 64, 0, stream>>>(pooled, fw, fb, out);
}

// Round 6
// 110.529 us; speedup vs baseline: 1.4221x; 1.4221x over previous
//
#include <hip/hip_runtime.h>

#define NN 100
#define CC 32
#define HEE 32
#define FF 64
#define TILE 10
#define ROWS 7   // rows per wave in k_layer
#define STRIP 25 // rows per block in k_layer

// ---------------- K1: hi = x@ew1[:C]+eb1, hj = x@ew1[C:], d0 ----------------
__global__ __launch_bounds__(64) void k_hidden(
    const float* __restrict__ x, const float* __restrict__ A,
    const float* __restrict__ ew1, const float* __restrict__ eb1,
    float* __restrict__ hi, float* __restrict__ hj, float* __restrict__ d0) {
  int bn = blockIdx.x;
  int t = threadIdx.x;
  __shared__ float xr[CC];
  if (t < CC) xr[t] = x[bn * CC + t];

  const float* arow = A + (size_t)bn * NN;
  float s = 0.f;
  for (int j = t; j < NN; j += 64) s += arow[j];
#pragma unroll
  for (int off = 32; off > 0; off >>= 1) s += __shfl_down(s, off);
  if (t == 0) d0[bn] = 1.0f / sqrtf(s + 1.0f + 1e-5f);

  __syncthreads();
  int k = t & 31;
  const float* w = ew1 + (t < 32 ? 0 : CC * HEE) + k;
  float acc = (t < 32) ? eb1[k] : 0.f;
#pragma unroll
  for (int c = 0; c < CC; ++c) acc += xr[c] * w[c * HEE];
  if (t < 32) hi[bn * HEE + k] = acc;
  else        hj[bn * HEE + k] = acc;
}

// ---------------- K2: Ahat1 = A_pred + I, d1 ----------------
__global__ __launch_bounds__(256) void k_edge(
    const float* __restrict__ hi, const float* __restrict__ hj,
    const float* __restrict__ ew2, const float* __restrict__ eb2,
    const float* __restrict__ mask,
    float* __restrict__ Ahat1, float* __restrict__ d1) {
  __shared__ __align__(16) float shi[NN * HEE];
  __shared__ __align__(16) float shj[NN * HEE];
  __shared__ __align__(16) float sw2[HEE];
  __shared__ float sm[NN];
  __shared__ float sA[TILE][NN];
  int t = threadIdx.x;
  int b = blockIdx.x / 10;
  int i0 = (blockIdx.x % 10) * TILE;

  const float4* hi4 = (const float4*)(hi + (size_t)b * NN * HEE);
  const float4* hj4 = (const float4*)(hj + (size_t)b * NN * HEE);
  float4* shi4 = (float4*)shi;
  float4* shj4 = (float4*)shj;
  for (int v = t; v < NN * 8; v += 256) {
    int j = v >> 3, k4 = v & 7;
    int sw = (j << 3) | (k4 ^ (j & 7));
    shi4[sw] = hi4[v];
    shj4[sw] = hj4[v];
  }
  if (t < HEE) sw2[t] = ew2[t];
  if (t < NN) sm[t] = mask[b * NN + t];
  __syncthreads();

  float e2 = eb2[0];
  float4* sw24 = (float4*)sw2;
  for (int p = t; p < TILE * NN; p += 256) {
    int r = p / NN, j = p % NN, i = i0 + r;
    float val;
    if (j == i) {
      val = 1.0f;
    } else {
      float a1 = 0.f, a2 = 0.f;
#pragma unroll
      for (int k4 = 0; k4 < 8; ++k4) {
        float4 hii = shi4[(i << 3) | (k4 ^ (i & 7))];
        float4 hji = shj4[(i << 3) | (k4 ^ (i & 7))];
        float4 hij = shi4[(j << 3) | (k4 ^ (j & 7))];
        float4 hjj = shj4[(j << 3) | (k4 ^ (j & 7))];
        float4 w4 = sw24[k4];
        a1 += fmaxf(hii.x + hjj.x, 0.f) * w4.x;
        a2 += fmaxf(hij.x + hji.x, 0.f) * w4.x;
        a1 += fmaxf(hii.y + hjj.y, 0.f) * w4.y;
        a2 += fmaxf(hij.y + hji.y, 0.f) * w4.y;
        a1 += fmaxf(hii.z + hjj.z, 0.f) * w4.z;
        a2 += fmaxf(hij.z + hji.z, 0.f) * w4.z;
        a1 += fmaxf(hii.w + hjj.w, 0.f) * w4.w;
        a2 += fmaxf(hij.w + hji.w, 0.f) * w4.w;
      }
      val = expf(0.5f * (a1 + a2) + e2) * sm[i] * sm[j];
    }
    sA[r][j] = val;
    Ahat1[((size_t)b * NN + i) * NN + j] = val;
  }
  __syncthreads();
  if (t < TILE) {
    float s = 0.f;
    for (int j = 0; j < NN; ++j) s += sA[t][j];
    d1[b * NN + i0 + t] = 1.0f / sqrtf(s + 1e-5f);
  }
}

// ---------------- K_pre: P[b][rel][i][f] = sum_c x[b][i][c] * gw0[rel*32+c][f] ----------------
__global__ __launch_bounds__(256, 2) void k_pre2(
    const float* __restrict__ x, const float* __restrict__ gw0,
    float* __restrict__ P) {
  int t = threadIdx.x;
  int b = blockIdx.x & 127;
  int q = blockIdx.x >> 7;
  int wid = __builtin_amdgcn_readfirstlane(t >> 6);
  int lane = t & 63;
  int rg = wid * 4 + q;
  int row0 = rg * 8;
  if (row0 >= NN) return;

  int rowc[8];
#pragma unroll
  for (int r = 0; r < 8; ++r) rowc[r] = min(row0 + r, NN - 1);

  float acc0[8], acc1[8];
#pragma unroll
  for (int r = 0; r < 8; ++r) { acc0[r] = 0.f; acc1[r] = 0.f; }

  for (int c4 = 0; c4 < CC / 4; ++c4) {
    int c = c4 * 4;
    float w00 = gw0[(size_t)c * 64 + lane];
    float w01 = gw0[(size_t)(c + 1) * 64 + lane];
    float w02 = gw0[(size_t)(c + 2) * 64 + lane];
    float w03 = gw0[(size_t)(c + 3) * 64 + lane];
    float w10 = gw0[(size_t)(CC + c) * 64 + lane];
    float w11 = gw0[(size_t)(CC + c + 1) * 64 + lane];
    float w12 = gw0[(size_t)(CC + c + 2) * 64 + lane];
    float w13 = gw0[(size_t)(CC + c + 3) * 64 + lane];
#pragma unroll
    for (int r = 0; r < 8; ++r) {
      float4 a4 = *(const float4*)(x + ((size_t)b * NN + rowc[r]) * CC + c);
      acc0[r] += a4.x * w00 + a4.y * w01 + a4.z * w02 + a4.w * w03;
      acc1[r] += a4.x * w10 + a4.y * w11 + a4.z * w12 + a4.w * w13;
    }
  }
#pragma unroll
  for (int r = 0; r < 8; ++r) {
    int row = row0 + r;
    if (row < NN) {
      P[(((size_t)b * 2 + 0) * NN + row) * 64 + lane] = acc0[r];
      P[(((size_t)b * 2 + 1) * NN + row) * 64 + lane] = acc1[r];
    }
  }
}

// ---------------- K_layer ----------------
// grid B*4, 256 threads. Block stages its 25-row A/Ah strip AND scaled P in LDS;
// compute loop is pure LDS->VALU (single in-order lgkmcnt domain, no SMEM mixing).
template <int LAST>
__global__ __launch_bounds__(256, 2) void k_layer(
    const float* __restrict__ A, const float* __restrict__ Ah1,
    const float* __restrict__ d0, const float* __restrict__ d1,
    const float* __restrict__ mask, const float* __restrict__ Pin,
    const float* __restrict__ bias, const float* __restrict__ Wn,
    float* __restrict__ Pout) {
  __shared__ __align__(16) float sP[2][NN][64];        // 51.2 KB, scaled by d[j]
  __shared__ __align__(16) float sA[2][STRIP][NN];     // 20 KB raw A / Ahat1 strip
  __shared__ __align__(16) float srow[4][ROWS][64];    // 7.2 KB per-wave out rows
  int t = threadIdx.x;
  int b = blockIdx.x >> 2;
  int q = blockIdx.x & 3;
  int r0 = q * STRIP;

  // stage sP[rel][j][f] = P[b][rel][j][f] * d_rel[j]
  {
    const float4* P4 = (const float4*)(Pin + (size_t)b * 12800);
    float4* sP4 = (float4*)&sP[0][0][0];
    const float* d0b = d0 + b * NN;
    const float* d1b = d1 + b * NN;
    for (int v = t; v < 3200; v += 256) {
      int rel = (v >= 1600) ? 1 : 0;
      int rem = v - rel * 1600;
      int j = rem >> 4;
      float dv = rel ? d1b[j] : d0b[j];
      float4 p = P4[v];
      p.x *= dv; p.y *= dv; p.z *= dv; p.w *= dv;
      sP4[v] = p;
    }
  }
  // stage sA: 2 rel x 25 rows x 100 (row stride 100 floats, 16B-aligned)
  {
    const float* A_b = A + (size_t)b * NN * NN + (size_t)r0 * NN;
    const float* Ah_b = Ah1 + (size_t)b * NN * NN + (size_t)r0 * NN;
    float4* sA4 = (float4*)&sA[0][0][0];
    for (int v = t; v < 2 * STRIP * NN / 4; v += 256) {
      int rel = (v >= 625) ? 1 : 0;
      int rem = v - rel * 625;
      const float* src = rel ? Ah_b : A_b;
      sA4[v] = *(const float4*)(src + rem * 4);
    }
  }
  __syncthreads();

  int wid = __builtin_amdgcn_readfirstlane(t >> 6);
  int lane = t & 63;
  int rw0 = wid * ROWS;  // 0,7,14,21

  int lr[ROWS];  // local row within strip (clamped -> duplicate rows benign)
#pragma unroll
  for (int r = 0; r < ROWS; ++r) lr[r] = min(rw0 + r, STRIP - 1);

  float acc0[ROWS], acc1[ROWS];
#pragma unroll
  for (int r = 0; r < ROWS; ++r) { acc0[r] = 0.f; acc1[r] = 0.f; }

  // ---- phase 1: pure-LDS GEMM chunk loop ----
#pragma unroll 5
  for (int j4 = 0; j4 < NN / 4; ++j4) {
    int j = j4 * 4;
    float cp0[4], cp1[4];
#pragma unroll
    for (int u = 0; u < 4; ++u) { cp0[u] = sP[0][j + u][lane]; cp1[u] = sP[1][j + u][lane]; }
#pragma unroll
    for (int r = 0; r < ROWS; ++r) {
      float4 a0 = *(const float4*)&sA[0][lr[r]][j];  // broadcast read
      float4 a1 = *(const float4*)&sA[1][lr[r]][j];
      acc0[r] += a0.x * cp0[0] + a0.y * cp0[1] + a0.z * cp0[2] + a0.w * cp0[3];
      acc1[r] += a1.x * cp1[0] + a1.y * cp1[1] + a1.z * cp1[2] + a1.w * cp1[3];
    }
  }

  float vb = bias[lane];
  const float* d0b = d0 + b * NN;
  const float* d1b = d1 + b * NN;
  const float* mb = mask + b * NN;
  float outv[ROWS];
#pragma unroll
  for (int r = 0; r < ROWS; ++r) {
    int gr = r0 + lr[r];
    float d0r = d0b[gr];
    float d1r = d1b[gr];
    float mr = mb[gr];
    float pdiag = sP[0][gr][lane];  // Pd0[row][lane]  (+I term of rel0)
    float v = (acc0[r] + pdiag) * d0r + acc1[r] * d1r;
    v = (v + vb) * mr;
    outv[r] = fmaxf(v, 0.f);
  }

  if (LAST) {
    float mx = outv[0];
#pragma unroll
    for (int r = 1; r < ROWS; ++r) mx = fmaxf(mx, outv[r]);
    Pout[((size_t)b * 16 + q * 4 + wid) * 64 + lane] = mx;
    return;
  }

  // ---- phase 2: P_next = out @ Wn (srow wave-private; W vector loads = vmcnt domain) ----
#pragma unroll
  for (int r = 0; r < ROWS; ++r) srow[wid][r][lane] = outv[r];

  float pacc0[ROWS], pacc1[ROWS];
#pragma unroll
  for (int r = 0; r < ROWS; ++r) { pacc0[r] = 0.f; pacc1[r] = 0.f; }

#pragma unroll 4
  for (int k4 = 0; k4 < 16; ++k4) {
    int k = k4 * 4;
    float w00 = Wn[(size_t)k * 64 + lane];
    float w01 = Wn[(size_t)(k + 1) * 64 + lane];
    float w02 = Wn[(size_t)(k + 2) * 64 + lane];
    float w03 = Wn[(size_t)(k + 3) * 64 + lane];
    float w10 = Wn[(size_t)(64 + k) * 64 + lane];
    float w11 = Wn[(size_t)(64 + k + 1) * 64 + lane];
    float w12 = Wn[(size_t)(64 + k + 2) * 64 + lane];
    float w13 = Wn[(size_t)(64 + k + 3) * 64 + lane];
#pragma unroll
    for (int r = 0; r < ROWS; ++r) {
      float4 s4 = *(const float4*)&srow[wid][r][k];  // broadcast read
      pacc0[r] += s4.x * w00 + s4.y * w01 + s4.z * w02 + s4.w * w03;
      pacc1[r] += s4.x * w10 + s4.y * w11 + s4.z * w12 + s4.w * w13;
    }
  }
#pragma unroll
  for (int r = 0; r < ROWS; ++r) {
    int row = r0 + lr[r];
    Pout[(((size_t)b * 2 + 0) * NN + row) * 64 + lane] = pacc0[r];
    Pout[(((size_t)b * 2 + 1) * NN + row) * 64 + lane] = pacc1[r];
  }
}

// ---------------- K_final: max over 16 rowgroup partials + classifier ----------------
__global__ __launch_bounds__(64) void k_final(
    const float* __restrict__ pooled, const float* __restrict__ fw,
    const float* __restrict__ fb, float* __restrict__ out) {
  int b = blockIdx.x;
  int t = threadIdx.x;
  __shared__ float sp[FF];
  float m = -3.402823466e38f;
  const float* pb = pooled + (size_t)b * 16 * 64;
#pragma unroll
  for (int rg = 0; rg < 16; ++rg) m = fmaxf(m, pb[rg * 64 + t]);
  sp[t] = m;
  __syncthreads();
  if (t < 16) {
    float acc = fb[t];
#pragma unroll
    for (int f = 0; f < FF; ++f) acc += sp[f] * fw[f * 16 + t];
    out[b * 16 + t] = acc;
  }
}

extern "C" void kernel_launch(void* const* d_in, const int* in_sizes, int n_in,
                              void* d_out, int out_size, void* d_ws, size_t ws_size,
                              hipStream_t stream) {
  const float* x    = (const float*)d_in[0];
  const float* A    = (const float*)d_in[1];
  const float* mask = (const float*)d_in[2];
  const float* ew1  = (const float*)d_in[3];
  const float* eb1  = (const float*)d_in[4];
  const float* ew2  = (const float*)d_in[5];
  const float* eb2  = (const float*)d_in[6];
  const float* gw0  = (const float*)d_in[7];
  const float* gb0  = (const float*)d_in[8];
  const float* gw1  = (const float*)d_in[9];
  const float* gb1  = (const float*)d_in[10];
  const float* gw2  = (const float*)d_in[11];
  const float* gb2  = (const float*)d_in[12];
  const float* fw   = (const float*)d_in[13];
  const float* fb   = (const float*)d_in[14];
  float* out = (float*)d_out;
  float* ws = (float*)d_ws;

  const int B = 128;
  float* hi  = ws;                   // 409600
  float* hj  = hi + 409600;          // 409600
  float* Ah1 = hj + 409600;          // 1280000
  float* d0  = Ah1 + 1280000;        // 12800
  float* d1  = d0 + 12800;           // 12800
  float* Pa  = d1 + 12800;           // 1638400  [B][2][100][64]
  float* Pb  = Pa + 1638400;         // 1638400
  float* pooled = Pb + 1638400;      // 128*16*64 = 131072

  k_hidden<<<B * NN, 64, 0, stream>>>(x, A, ew1, eb1, hi, hj, d0);
  k_edge<<<B * 10, 256, 0, stream>>>(hi, hj, ew2, eb2, mask, Ah1, d1);
  k_pre2<<<512, 256, 0, stream>>>(x, gw0, Pa);
  k_layer<0><<<B * 4, 256, 0, stream>>>(A, Ah1, d0, d1, mask, Pa, gb0, gw1, Pb);
  k_layer<0><<<B * 4, 256, 0, stream>>>(A, Ah1, d0, d1, mask, Pb, gb1, gw2, Pa);
  k_layer<1><<<B * 4, 256, 0, stream>>>(A, Ah1, d0, d1, mask, Pa, gb2, gw2, pooled);
  k_final<<<B, 64, 0, stream>>>(pooled, fw, fb, out);
}